// Round 1
// baseline (298.051 us; speedup 1.0000x reference)
//
#include <hip/hip_runtime.h>

#define B_    64
#define C_    2048
#define HW_   288
#define EPS_  0.07f
#define TINY_ 1e-8f

// ---------------------------------------------------------------------------
// Kernel 1: per-token partial sums over a C-chunk.
// grid = B*nch blocks, 256 threads. Block (b, ch) accumulates, for each of the
// 288 spatial tokens h: sum_c x^2, sum_c x*anchor0, sum_c x*anchor1 over its
// chunk of C. Planar output part[j][bi][h], j in {sq, d0, d1}.
// Coalesced: threads 0..255 read row floats h=t, threads 0..31 read h=256+t.
// ---------------------------------------------------------------------------
__global__ __launch_bounds__(256) void k1_partials(
    const float* __restrict__ x, const float* __restrict__ anchors,
    float* __restrict__ part, int nch, int cpc) {
  int bi = blockIdx.x;
  int b  = bi / nch;
  int ch = bi - b * nch;
  int t  = threadIdx.x;
  const float* xb  = x + ((size_t)b * C_ + (size_t)ch * cpc) * HW_;
  const float* a0p = anchors + ch * cpc;
  const float* a1p = anchors + C_ + ch * cpc;
  float ssq = 0.f, sd0 = 0.f, sd1 = 0.f;
  float ssqb = 0.f, sd0b = 0.f, sd1b = 0.f;
#pragma unroll 4
  for (int c = 0; c < cpc; ++c) {
    float a0 = a0p[c], a1 = a1p[c];
    float v = xb[(size_t)c * HW_ + t];
    ssq += v * v; sd0 += v * a0; sd1 += v * a1;
    if (t < HW_ - 256) {
      float w = xb[(size_t)c * HW_ + 256 + t];
      ssqb += w * w; sd0b += w * a0; sd1b += w * a1;
    }
  }
  int PS = gridDim.x * HW_;  // plane stride = B*nch*288
  int base = bi * HW_ + t;
  part[base] = ssq; part[PS + base] = sd0; part[2 * PS + base] = sd1;
  if (t < HW_ - 256) {
    int base2 = bi * HW_ + 256 + t;
    part[base2] = ssqb; part[PS + base2] = sd0b; part[2 * PS + base2] = sd1b;
  }
}

// Block-wide 2-value sum reduction for 320 threads (5 full waves).
// Result broadcast to all threads in p0/p1.
__device__ __forceinline__ void block_reduce2(
    float& p0, float& p1, volatile float* red0, volatile float* red1,
    int t, int nw) {
  int lane = t & 63, wid = t >> 6;
#pragma unroll
  for (int off = 32; off >= 1; off >>= 1) {
    p0 += __shfl_down(p0, off);
    p1 += __shfl_down(p1, off);
  }
  __syncthreads();   // protect red from previous round's readers
  if (lane == 0) { red0[wid] = p0; red1[wid] = p1; }
  __syncthreads();
  float s0 = 0.f, s1 = 0.f;
  for (int w = 0; w < nw; ++w) { s0 += red0[w]; s1 += red1[w]; }
  p0 = s0; p1 = s1;
}

// ---------------------------------------------------------------------------
// Kernel 2: per-batch Sinkhorn. grid = 64 blocks, 320 threads (5 waves;
// threads >= 288 contribute zeros). Writes m to d_out's m region, 1/den to ws.
// ---------------------------------------------------------------------------
__global__ __launch_bounds__(320) void k2_sinkhorn(
    const float* __restrict__ part, const float* __restrict__ anchors,
    int nch, float* __restrict__ out_m, float* __restrict__ invden) {
  int b = blockIdx.x, t = threadIdx.x;
  __shared__ float red0[8], red1[8];
  const int nw = 5;

  // anchor norms (each of 2 anchors over C=2048)
  float a0 = 0.f, a1 = 0.f;
  for (int c = t; c < C_; c += 320) {
    float q0 = anchors[c], q1 = anchors[C_ + c];
    a0 += q0 * q0; a1 += q1 * q1;
  }
  block_reduce2(a0, a1, red0, red1, t, nw);
  float ian0 = 1.0f / fmaxf(sqrtf(a0), 1e-12f);
  float ian1 = 1.0f / fmaxf(sqrtf(a1), 1e-12f);

  // per-token K values
  float K0 = 0.f, K1 = 0.f;
  if (t < HW_) {
    int PS = B_ * nch * HW_;
    float ssq = 0.f, d0 = 0.f, d1 = 0.f;
    for (int ch = 0; ch < nch; ++ch) {
      int base = (b * nch + ch) * HW_ + t;
      ssq += part[base]; d0 += part[PS + base]; d1 += part[2 * PS + base];
    }
    float ixn = 1.0f / fmaxf(sqrtf(ssq), 1e-12f);
    float cos0 = d0 * ixn * ian0;
    float cos1 = d1 * ixn * ian1;
    K0 = expf((cos0 - 1.0f) / EPS_) + TINY_;
    K1 = expf((cos1 - 1.0f) / EPS_) + TINY_;
  }

  // Sinkhorn iterations: u = a/(K v + TINY); v = b/(K^T u + TINY)
  float v0 = 1.f, v1 = 1.f, u = 0.f;
  for (int it = 0; it < 7; ++it) {
    if (t < HW_) u = (1.0f / (float)HW_) / (K0 * v0 + K1 * v1 + TINY_);
    float p0 = K0 * u, p1 = K1 * u;  // zero for t >= 288 (K=0)
    block_reduce2(p0, p1, red0, red1, t, nw);
    v0 = 0.5f / (p0 + TINY_);        // computed redundantly by all threads
    v1 = 0.5f / (p1 + TINY_);
  }

  float m0 = 0.f, m1 = 0.f;
  if (t < HW_) {
    m0 = K0 * u * v0 * (float)HW_;
    m1 = K1 * u * v1 * (float)HW_;
  }
  float q0 = m0, q1 = m1;
  block_reduce2(q0, q1, red0, red1, t, nw);
  if (t < HW_) {
    out_m[(b * 2 + 0) * HW_ + t] = m0;
    out_m[(b * 2 + 1) * HW_ + t] = m1;
  }
  if (t == 0) {
    invden[b * 2 + 0] = 1.0f / (q0 + 1e-6f);
    invden[b * 2 + 1] = 1.0f / (q1 + 1e-6f);
  }
}

// ---------------------------------------------------------------------------
// Kernel 3: masked pooling num[b,k,c] = sum_h x[b,c,h]*m[b,k,h], /den.
// grid = 64*16 blocks, 256 threads. Wave-per-row: lane l reads float4 #l of
// the 288-float row (72 float4: full 64-lane read + 8-lane tail), dots against
// per-lane m fragments preloaded from LDS, 64-lane shuffle reduce.
// ---------------------------------------------------------------------------
__global__ __launch_bounds__(256) void k3_pool(
    const float* __restrict__ x, const float* __restrict__ m,
    const float* __restrict__ invden, float* __restrict__ out) {
  int bi = blockIdx.x;
  int b = bi >> 4, tile = bi & 15;
  int t = threadIdx.x, lane = t & 63, wid = t >> 6;
  __shared__ float sm0[HW_], sm1[HW_];
  __shared__ float sinv[2];
  for (int i = t; i < HW_; i += 256) {
    sm0[i] = m[(b * 2 + 0) * HW_ + i];
    sm1[i] = m[(b * 2 + 1) * HW_ + i];
  }
  if (t == 0) { sinv[0] = invden[b * 2]; sinv[1] = invden[b * 2 + 1]; }
  __syncthreads();

  float ma0[4], ma1[4], mb0[4], mb1[4];
#pragma unroll
  for (int j = 0; j < 4; ++j) {
    ma0[j] = sm0[4 * lane + j];
    ma1[j] = sm1[4 * lane + j];
  }
  bool tail = lane < 8;
#pragma unroll
  for (int j = 0; j < 4; ++j) {
    mb0[j] = tail ? sm0[256 + 4 * lane + j] : 0.f;
    mb1[j] = tail ? sm1[256 + 4 * lane + j] : 0.f;
  }
  float inv0 = sinv[0], inv1 = sinv[1];

  int c0 = tile * 128 + wid * 32;
  for (int r = 0; r < 32; ++r) {
    int c = c0 + r;
    const float4* xr = (const float4*)(x + ((size_t)b * C_ + c) * HW_);
    float4 xa = xr[lane];
    float acc0 = xa.x * ma0[0] + xa.y * ma0[1] + xa.z * ma0[2] + xa.w * ma0[3];
    float acc1 = xa.x * ma1[0] + xa.y * ma1[1] + xa.z * ma1[2] + xa.w * ma1[3];
    if (tail) {
      float4 xb = xr[64 + lane];
      acc0 += xb.x * mb0[0] + xb.y * mb0[1] + xb.z * mb0[2] + xb.w * mb0[3];
      acc1 += xb.x * mb1[0] + xb.y * mb1[1] + xb.z * mb1[2] + xb.w * mb1[3];
    }
#pragma unroll
    for (int off = 32; off >= 1; off >>= 1) {
      acc0 += __shfl_down(acc0, off);
      acc1 += __shfl_down(acc1, off);
    }
    if (lane == 0) {
      out[(size_t)b * C_ + c] = acc0 * inv0;                       // c0_vec
      out[(size_t)B_ * C_ + (size_t)b * C_ + c] = acc1 * inv1;     // c1_vec
    }
  }
}

extern "C" void kernel_launch(void* const* d_in, const int* in_sizes, int n_in,
                              void* d_out, int out_size, void* d_ws, size_t ws_size,
                              hipStream_t stream) {
  const float* x       = (const float*)d_in[0];
  const float* anchors = (const float*)d_in[1];
  float* out = (float*)d_out;

  // ws layout: [0..127] invden (B*2=128 used), then partials (planar, 3 planes)
  float* invden = (float*)d_ws;
  int nch = 16;
  while (nch > 1 && (size_t)(128 + 3 * B_ * nch * HW_) * sizeof(float) > ws_size)
    nch >>= 1;
  float* part = invden + 128;
  int cpc = C_ / nch;

  float* out_m = out + 2 * B_ * C_;  // m region of d_out (B,2,H,W)

  k1_partials<<<B_ * nch, 256, 0, stream>>>(x, anchors, part, nch, cpc);
  k2_sinkhorn<<<B_, 320, 0, stream>>>(part, anchors, nch, out_m, invden);
  k3_pool<<<B_ * 16, 256, 0, stream>>>(x, out_m, invden, out);
}

// Round 2
// 266.189 us; speedup vs baseline: 1.1197x; 1.1197x over previous
//
#include <hip/hip_runtime.h>

#define B_    64
#define C_    2048
#define HW_   288
#define EPS_  0.07f
#define TINY_ 1e-8f

// ---------------------------------------------------------------------------
// Kernel 1: per-token partial sums, one C-chunk per WAVE.
// grid = B * nch/4 blocks, 256 threads (4 waves, each wave owns chunk
// ch = cg*4 + wid). Lane l accumulates h = 4l..4l+3 (float4) plus tail
// h = 256+4l..256+4l+3 for lanes 0..7. Fully coalesced float4 loads/stores.
// part layout: [3 planes][B*nch][288].
// ---------------------------------------------------------------------------
__device__ __forceinline__ void acc3(const float4 v, float a0, float a1,
                                     float* ssq, float* sd0, float* sd1) {
  ssq[0] += v.x * v.x; ssq[1] += v.y * v.y; ssq[2] += v.z * v.z; ssq[3] += v.w * v.w;
  sd0[0] += v.x * a0;  sd0[1] += v.y * a0;  sd0[2] += v.z * a0;  sd0[3] += v.w * a0;
  sd1[0] += v.x * a1;  sd1[1] += v.y * a1;  sd1[2] += v.z * a1;  sd1[3] += v.w * a1;
}

__global__ __launch_bounds__(256) void k1_partials(
    const float* __restrict__ x, const float* __restrict__ anchors,
    float* __restrict__ part, int nch, int cpc) {
  int bi = blockIdx.x;
  int nblk = nch >> 2;            // chunk-groups per b
  int b  = bi / nblk;
  int cg = bi - b * nblk;
  int t = threadIdx.x, lane = t & 63, wid = t >> 6;
  int ch = cg * 4 + wid;          // this wave's chunk
  int c0 = ch * cpc;
  const float* xb = x + ((size_t)b * C_ + c0) * HW_;
  bool tail = lane < 8;

  float ssq[4] = {0,0,0,0}, sd0[4] = {0,0,0,0}, sd1[4] = {0,0,0,0};
  float tsq[4] = {0,0,0,0}, td0[4] = {0,0,0,0}, td1[4] = {0,0,0,0};

#pragma unroll 4
  for (int r = 0; r < cpc; ++r) {
    const float4* xr = (const float4*)(xb + (size_t)r * HW_);
    float a0 = anchors[c0 + r];
    float a1 = anchors[C_ + c0 + r];
    float4 xa = xr[lane];
    acc3(xa, a0, a1, ssq, sd0, sd1);
    if (tail) {
      float4 xc = xr[64 + lane];
      acc3(xc, a0, a1, tsq, td0, td1);
    }
  }

  size_t PS = (size_t)B_ * nch * HW_;
  float* base = part + (size_t)(b * nch + ch) * HW_;
  float4* p0 = (float4*)base;
  float4* p1 = (float4*)(base + PS);
  float4* p2 = (float4*)(base + 2 * PS);
  p0[lane] = make_float4(ssq[0], ssq[1], ssq[2], ssq[3]);
  p1[lane] = make_float4(sd0[0], sd0[1], sd0[2], sd0[3]);
  p2[lane] = make_float4(sd1[0], sd1[1], sd1[2], sd1[3]);
  if (tail) {
    p0[64 + lane] = make_float4(tsq[0], tsq[1], tsq[2], tsq[3]);
    p1[64 + lane] = make_float4(td0[0], td0[1], td0[2], td0[3]);
    p2[64 + lane] = make_float4(td1[0], td1[1], td1[2], td1[3]);
  }
}

// ---------------------------------------------------------------------------
// Kernel 1b: collapse nch chunk-partials -> red[3][B][288].
// grid = 3*B*288/256 = 216 blocks.
// ---------------------------------------------------------------------------
__global__ __launch_bounds__(256) void k1b_reduce(
    const float* __restrict__ part, float* __restrict__ red, int nch) {
  int idx = blockIdx.x * 256 + threadIdx.x;       // < 3*64*288 = 55296
  int plane = idx / (B_ * HW_);
  int rem = idx - plane * (B_ * HW_);
  int b = rem / HW_;
  int h = rem - b * HW_;
  const float* p = part + (size_t)plane * B_ * nch * HW_ + (size_t)b * nch * HW_ + h;
  float s = 0.f;
#pragma unroll 8
  for (int ch = 0; ch < nch; ++ch) s += p[(size_t)ch * HW_];
  red[idx] = s;
}

// Block-wide 2-value sum reduction for 320 threads (5 full waves).
__device__ __forceinline__ void block_reduce2(
    float& p0, float& p1, volatile float* red0, volatile float* red1,
    int t, int nw) {
  int lane = t & 63, wid = t >> 6;
#pragma unroll
  for (int off = 32; off >= 1; off >>= 1) {
    p0 += __shfl_down(p0, off);
    p1 += __shfl_down(p1, off);
  }
  __syncthreads();
  if (lane == 0) { red0[wid] = p0; red1[wid] = p1; }
  __syncthreads();
  float s0 = 0.f, s1 = 0.f;
  for (int w = 0; w < nw; ++w) { s0 += red0[w]; s1 += red1[w]; }
  p0 = s0; p1 = s1;
}

// ---------------------------------------------------------------------------
// Kernel 2: per-batch Sinkhorn. grid = 64 blocks, 320 threads.
// ---------------------------------------------------------------------------
__global__ __launch_bounds__(320) void k2_sinkhorn(
    const float* __restrict__ red, const float* __restrict__ anchors,
    float* __restrict__ out_m, float* __restrict__ invden) {
  int b = blockIdx.x, t = threadIdx.x;
  __shared__ float red0[8], red1[8];
  const int nw = 5;

  float a0 = 0.f, a1 = 0.f;
  for (int c = t; c < C_; c += 320) {
    float q0 = anchors[c], q1 = anchors[C_ + c];
    a0 += q0 * q0; a1 += q1 * q1;
  }
  block_reduce2(a0, a1, red0, red1, t, nw);
  float ian0 = 1.0f / fmaxf(sqrtf(a0), 1e-12f);
  float ian1 = 1.0f / fmaxf(sqrtf(a1), 1e-12f);

  float K0 = 0.f, K1 = 0.f;
  if (t < HW_) {
    float ssq = red[b * HW_ + t];
    float d0  = red[B_ * HW_ + b * HW_ + t];
    float d1  = red[2 * B_ * HW_ + b * HW_ + t];
    float ixn = 1.0f / fmaxf(sqrtf(ssq), 1e-12f);
    float cos0 = d0 * ixn * ian0;
    float cos1 = d1 * ixn * ian1;
    K0 = expf((cos0 - 1.0f) / EPS_) + TINY_;
    K1 = expf((cos1 - 1.0f) / EPS_) + TINY_;
  }

  float v0 = 1.f, v1 = 1.f, u = 0.f;
  for (int it = 0; it < 7; ++it) {
    if (t < HW_) u = (1.0f / (float)HW_) / (K0 * v0 + K1 * v1 + TINY_);
    float p0 = K0 * u, p1 = K1 * u;
    block_reduce2(p0, p1, red0, red1, t, nw);
    v0 = 0.5f / (p0 + TINY_);
    v1 = 0.5f / (p1 + TINY_);
  }

  float m0 = 0.f, m1 = 0.f;
  if (t < HW_) {
    m0 = K0 * u * v0 * (float)HW_;
    m1 = K1 * u * v1 * (float)HW_;
  }
  float q0 = m0, q1 = m1;
  block_reduce2(q0, q1, red0, red1, t, nw);
  if (t < HW_) {
    out_m[(b * 2 + 0) * HW_ + t] = m0;
    out_m[(b * 2 + 1) * HW_ + t] = m1;
  }
  if (t == 0) {
    invden[b * 2 + 0] = 1.0f / (q0 + 1e-6f);
    invden[b * 2 + 1] = 1.0f / (q1 + 1e-6f);
  }
}

// ---------------------------------------------------------------------------
// Kernel 3: masked pooling. Two threads per c-row; each dots half the row
// (36 float4) against m broadcast from LDS; single shfl_down(1) to combine.
// grid = B*16 blocks (128 rows each), 256 threads.
// ---------------------------------------------------------------------------
__global__ __launch_bounds__(256) void k3_pool(
    const float* __restrict__ x, const float* __restrict__ m,
    const float* __restrict__ invden, float* __restrict__ out) {
  int bi = blockIdx.x;
  int b = bi >> 4, seg = bi & 15;
  int t = threadIdx.x;
  int lr = t >> 1, half = t & 1;
  int c = seg * 128 + lr;

  __shared__ float4 sm0[72], sm1[72];
  __shared__ float sinv[2];
  if (t < 72)       sm0[t]      = ((const float4*)(m + (b * 2 + 0) * HW_))[t];
  else if (t < 144) sm1[t - 72] = ((const float4*)(m + (b * 2 + 1) * HW_))[t - 72];
  if (t == 0) { sinv[0] = invden[2 * b]; sinv[1] = invden[2 * b + 1]; }
  __syncthreads();

  const float4* xr = (const float4*)(x + ((size_t)b * C_ + c) * HW_) + half * 36;
  const float4* w0p = sm0 + half * 36;
  const float4* w1p = sm1 + half * 36;
  float acc0 = 0.f, acc1 = 0.f;
#pragma unroll 4
  for (int i = 0; i < 36; ++i) {
    float4 xa = xr[i];
    float4 w0 = w0p[i];
    float4 w1 = w1p[i];
    acc0 += xa.x * w0.x + xa.y * w0.y + xa.z * w0.z + xa.w * w0.w;
    acc1 += xa.x * w1.x + xa.y * w1.y + xa.z * w1.z + xa.w * w1.w;
  }
  acc0 += __shfl_down(acc0, 1);
  acc1 += __shfl_down(acc1, 1);
  if (half == 0) {
    out[(size_t)b * C_ + c] = acc0 * sinv[0];
    out[(size_t)B_ * C_ + (size_t)b * C_ + c] = acc1 * sinv[1];
  }
}

extern "C" void kernel_launch(void* const* d_in, const int* in_sizes, int n_in,
                              void* d_out, int out_size, void* d_ws, size_t ws_size,
                              hipStream_t stream) {
  const float* x       = (const float*)d_in[0];
  const float* anchors = (const float*)d_in[1];
  float* out = (float*)d_out;

  // ws layout: invden[128] | red[3*64*288] | part[3*B*nch*288]
  float* invden = (float*)d_ws;
  float* red = invden + 128;
  float* part = red + 3 * B_ * HW_;
  int nch = 128;
  while (nch > 4 &&
         (size_t)(128 + 3 * B_ * HW_ + 3 * B_ * nch * HW_) * sizeof(float) > ws_size)
    nch >>= 1;
  int cpc = C_ / nch;

  float* out_m = out + 2 * B_ * C_;  // m region of d_out (B,2,H,W)

  k1_partials<<<B_ * (nch / 4), 256, 0, stream>>>(x, anchors, part, nch, cpc);
  k1b_reduce<<<(3 * B_ * HW_) / 256, 256, 0, stream>>>(part, red, nch);
  k2_sinkhorn<<<B_, 320, 0, stream>>>(red, anchors, out_m, invden);
  k3_pool<<<B_ * 16, 256, 0, stream>>>(x, out_m, invden, out);
}